// Round 5
// baseline (336.796 us; speedup 1.0000x reference)
//
#include <hip/hip_runtime.h>
#include <hip/hip_bf16.h>
#include <stdint.h>

typedef unsigned short u16;
typedef unsigned int   u32;
typedef __bf16 bf16x8 __attribute__((ext_vector_type(8)));
typedef float  f32x4  __attribute__((ext_vector_type(4)));

#define BATCH 32
#define CIN   128
#define HH    56
#define WW    56
#define OC    256
#define HP    58
#define WP    58
#define PLANE  (HH*WW)    // 3136
#define KDIM   1152       // CIN*9
#define NKT    36         // KDIM/32

#define XPAD_ELEMS (BATCH*HP*WP*CIN)   // NHWC padded bf16: 13,778,944
#define W3_ELEMS   (OC*KDIM)           // 294,912 bf16

// ---- prep 0: zero top/bottom padded rows (h=0 and h=57 per image) ----
__global__ void zero_border(uint4* __restrict__ xp4) {
    int i = blockIdx.x * 256 + threadIdx.x;       // uint4 index
    if (i >= 64 * 928) return;                    // 64 rows x 928 uint4/row
    int row = i / 928;
    int off = i - row * 928;
    int b = row >> 1;
    int h = (row & 1) ? (HP - 1) : 0;
    xp4[((size_t)(b * HP + h) * WP * CIN) / 8 + off] = (uint4){0, 0, 0, 0};
}

// ---- prep 1: NCHW fp32 -> NHWC bf16, interior + left/right borders ----
// block = (h, b); handles one (b, h): 128 ch x 56 w -> padded row of 58 w
__global__ __launch_bounds__(256) void pad_tr(const float* __restrict__ x,
                                              u16* __restrict__ xpad) {
    __shared__ u16 T16[56 * 130];   // [w][c], +2 pad -> bank stride 65 dwords
    const int h = blockIdx.x;
    const int b = blockIdx.y;
    const int tid = threadIdx.x;

    const float* src = x + (size_t)b * CIN * PLANE + h * WW;
#pragma unroll
    for (int j = 0; j < 28; ++j) {              // 28*256 = 7168 = 128*56
        int flat = j * 256 + tid;
        int c = flat / 56;
        int w = flat - c * 56;
        float v = src[(size_t)c * PLANE + w];
        __hip_bfloat16 bv = __float2bfloat16(v);
        T16[w * 130 + c] = *(u16*)&bv;
    }
    __syncthreads();

    // write full padded row: 58 positions x 128 ch = 928 uint4
    const u32* T32 = (const u32*)T16;
    uint4* dst = (uint4*)(xpad + (size_t)(b * HP + h + 1) * WP * CIN);
#pragma unroll
    for (int j = 0; j < 4; ++j) {
        int g = j * 256 + tid;
        if (g < 928) {
            int wp = g >> 4, cq = g & 15;       // 16 uint4 = 128 ch per wp
            uint4 v = (uint4){0, 0, 0, 0};
            if (wp >= 1 && wp <= 56) {
                int w = wp - 1;
                v.x = T32[w * 65 + cq * 4 + 0];
                v.y = T32[w * 65 + cq * 4 + 1];
                v.z = T32[w * 65 + cq * 4 + 2];
                v.w = T32[w * 65 + cq * 4 + 3];
            }
            dst[g] = v;
        }
    }
}

// ---- prep 2: W[OC][C*9] fp32 -> bf16 tiled w3[nt][kt][ni128][ci32] ----
// k ordering: k = r*128 + c  (r = kh*3+kw)
__global__ void pack_w(const float* __restrict__ W, u16* __restrict__ w3) {
    int o = blockIdx.x * blockDim.x + threadIdx.x;
    if (o >= W3_ELEMS) return;
    int nt   = o / (NKT * 4096);
    int rem  = o - nt * (NKT * 4096);
    int kt   = rem / 4096;
    int rem2 = rem - kt * 4096;
    int ni   = rem2 >> 5;
    int ci   = rem2 & 31;
    int n = nt * 128 + ni;
    int r = kt >> 2;                 // 0..8
    int c = ((kt & 3) << 5) + ci;    // 0..127
    float val = W[n * KDIM + c * 9 + r];
    __hip_bfloat16 bv = __float2bfloat16(val);
    w3[o] = *(u16*)&bv;
}

// ---------------- main: implicit GEMM, NO LDS, NO BARRIERS ----------------
// Both MFMA fragments load directly global->VGPR as dwordx4:
//   A (weights, packed): lane-contiguous, coalesced, L2-hot (288 KB)
//   B (x NHWC): 16 consecutive 256B rows per frag, 64B/lane segments
// Each wave self-paces via compiler-inserted s_waitcnt vmcnt(N); prefetch
// distance 1 (next kt's 8 loads in flight across current kt's 16 MFMAs).
// XCD swizzle: bx&7 -> XCD, contiguous 98 m-blocks per XCD (~3.3 MB L2 window)
__global__ __launch_bounds__(256, 3) void conv_main(
    const u16* __restrict__ xpad,
    const u16* __restrict__ w3,
    const float* __restrict__ bias,
    float* __restrict__ out)
{
    const int tid  = threadIdx.x;
    const int lane = tid & 63;
    const int wv   = tid >> 6;
    const int bx   = blockIdx.x;
    const int m0   = ((bx & 7) * 98 + (bx >> 3)) * 128;   // XCD-contiguous m
    const int nt   = blockIdx.y;

    const int wn = wv >> 1, wm = wv & 1;
    const int l16 = lane & 15, quad = lane >> 4;

    // A-frag per-lane byte offsets within a kt block (row*64 + quad*16)
    int aoff[4];
#pragma unroll
    for (int f = 0; f < 4; ++f)
        aoff[f] = (wn * 64 + f * 16 + l16) * 64 + quad * 16;

    // B-frag per-lane row byte offsets (constant across kt) + quad chunk
    size_t rowoff[4];
#pragma unroll
    for (int g = 0; g < 4; ++g) {
        int m  = m0 + wm * 64 + g * 16 + l16;
        int bb = m / PLANE;
        int s  = m - bb * PLANE;
        int hh = s / WW;
        int ww = s - hh * WW;
        rowoff[g] = ((size_t)((bb * HP + hh) * WP + ww) * CIN) * 2 + quad * 16;
    }

    const char* w3t = (const char*)(w3 + (size_t)nt * (NKT * 4096));
    const char* xb  = (const char*)xpad;

    f32x4 acc[4][4];
#pragma unroll
    for (int f = 0; f < 4; ++f) {
        f32x4 bv = *(const f32x4*)&bias[nt * 128 + wn * 64 + f * 16 + quad * 4];
#pragma unroll
        for (int g = 0; g < 4; ++g) acc[f][g] = bv;
    }

    uint4 Ar[2][4], Br[2][4];
    auto loadk = [&](int s, int kt) {
        const char* ab = w3t + (size_t)kt * 8192;
#pragma unroll
        for (int f = 0; f < 4; ++f)
            Ar[s][f] = *(const uint4*)(ab + aoff[f]);
        const int r  = kt >> 2;
        const int kh = r / 3;
        const int kw = r - kh * 3;
        const char* bb = xb + ((size_t)(kh * WP + kw) * CIN + (kt & 3) * 32) * 2;
#pragma unroll
        for (int g = 0; g < 4; ++g)
            Br[s][g] = *(const uint4*)(bb + rowoff[g]);
    };

    loadk(0, 0);
#pragma unroll
    for (int kt = 0; kt < NKT; ++kt) {
        const int cur = kt & 1;
        if (kt + 1 < NKT) loadk(cur ^ 1, kt + 1);
#pragma unroll
        for (int f = 0; f < 4; ++f) {
            union { uint4 u; bf16x8 b; } av; av.u = Ar[cur][f];
#pragma unroll
            for (int g = 0; g < 4; ++g) {
                union { uint4 u; bf16x8 b; } bvu; bvu.u = Br[cur][g];
                acc[f][g] = __builtin_amdgcn_mfma_f32_16x16x32_bf16(
                    av.b, bvu.b, acc[f][g], 0, 0, 0);
            }
        }
    }

    // epilogue: D row = oc (quad*4+reg), col = spatial m (lane&15)
    const int n0 = nt * 128 + wn * 64;
#pragma unroll
    for (int g = 0; g < 4; ++g) {
        const int mm = m0 + wm * 64 + g * 16 + l16;
        const int bb = mm / PLANE;
        const int ss = mm - bb * PLANE;
        float* obase = out + (size_t)bb * (OC * PLANE) + ss;
#pragma unroll
        for (int f = 0; f < 4; ++f) {
#pragma unroll
            for (int i = 0; i < 4; ++i) {
                const int n = n0 + f * 16 + quad * 4 + i;
                obase[(size_t)n * PLANE] = acc[f][g][i];
            }
        }
    }
}

extern "C" void kernel_launch(void* const* d_in, const int* in_sizes, int n_in,
                              void* d_out, int out_size, void* d_ws, size_t ws_size,
                              hipStream_t stream) {
    const float* x    = (const float*)d_in[0];
    const float* W    = (const float*)d_in[1];
    const float* bias = (const float*)d_in[2];
    float* out = (float*)d_out;

    u16* xpad = (u16*)d_ws;
    u16* w3   = xpad + XPAD_ELEMS;

    zero_border<<<232, 256, 0, stream>>>((uint4*)xpad);
    pad_tr<<<dim3(HH, BATCH), 256, 0, stream>>>(x, xpad);
    pack_w<<<(W3_ELEMS + 255) / 256, 256, 0, stream>>>(W, w3);

    dim3 grid(784, 2);
    conv_main<<<grid, 256, 0, stream>>>(xpad, w3, bias, out);
}